// Round 8
// baseline (14.846 us; speedup 1.0000x reference)
//
#include <hip/hip_runtime.h>

// out[n,d,oc,r] = logsumexp_ic( x[n,0,d,ic,r] + w[d,ic,oc,r] )
//              = log( sum_ic exp(x) * exp(w) )
// Batched GEMM over (d,r): K=IC=32 = one v_mfma_f32_16x16x32_bf16 per tile.
//
// R8 = R7 with the compile fix (manual RTNE bf16 packing instead of
// __builtin_bit_cast(__hip_bfloat162)).
// Occupancy attack: block = (d, 32n, 4r-half): grid 64x8x2 = 1024 blocks
// = 4 blocks/CU = 16 waves/CU. Per block: 16 KiB LDS, 8 global float4
// loads up-front, 32 exp + 16 log per thread. Independent barrier domains
// drift out of phase -> reads/VALU/MFMA/writes from different blocks overlap.

typedef __attribute__((ext_vector_type(8))) short bf16x8;
typedef __attribute__((ext_vector_type(4))) float f32x4;

constexpr int kD = 64, kIC = 32, kOC = 32, kR = 8;

__device__ __forceinline__ unsigned short f2bf(float f) {
    unsigned u = __builtin_bit_cast(unsigned, f);
    u += 0x7FFFu + ((u >> 16) & 1u);          // RTNE (inputs positive finite)
    return (unsigned short)(u >> 16);
}
__device__ __forceinline__ unsigned pk2(float a, float b) {
    return (unsigned)f2bf(a) | ((unsigned)f2bf(b) << 16);
}

__global__ __launch_bounds__(256) void lse_kernel(
    const float* __restrict__ x, const float* __restrict__ w,
    float* __restrict__ out)
{
    // frag-ordered bf16, 4 r per block: [tile(2)][r(4)][lane(64)][slot(8)]
    __shared__ __align__(16) unsigned short wsm[2 * 4 * 64 * 8];  // 8 KiB
    __shared__ __align__(16) unsigned short xs [2 * 4 * 64 * 8];  // 8 KiB

    const int t  = threadIdx.x;
    const int d  = blockIdx.x;
    const int n0 = blockIdx.y * 32;
    const int rh = blockIdx.z;            // r = rh*4 + j

    const int c  = t & 7;                 // ic selector: ic in {2c,2c+1,2c+16,2c+17}
    const int hi = t >> 3;                // w: oc 0..31  /  x: n row 0..31

    // ---- issue all 8 global float4 loads up front (each = 4 r values)
    const float* wd = w + (size_t)d * (kIC * kOC * kR);
    const float* xr = x + (size_t)(n0 + hi) * (kD * kIC * kR) + (size_t)d * (kIC * kR);
    float4 wv[2][2], xv[2][2];
    #pragma unroll
    for (int a = 0; a < 2; ++a)
        #pragma unroll
        for (int p = 0; p < 2; ++p) {
            const int ic = 2 * c + 16 * a + p;
            wv[a][p] = *reinterpret_cast<const float4*>(wd + (size_t)ic * 256 + hi * 8 + rh * 4);
            xv[a][p] = *reinterpret_cast<const float4*>(xr + ic * 8 + rh * 4);
        }

    // ---- exp -> bf16 pairs -> frag-ordered LDS (b32 writes, 2-way banks = free)
    const int g0 = c >> 2, s = 2 * (c & 3);
    const int col = hi & 15, u = hi >> 4;   // w: (oc-lane, oc-tile) / x: (row-lane, n-tile)
    #pragma unroll
    for (int a = 0; a < 2; ++a) {
        const int g = g0 + 2 * a;           // ic-group = slot-group of lane l>>4
        #pragma unroll
        for (int j = 0; j < 4; ++j) {
            const float* w0 = reinterpret_cast<const float*>(&wv[a][0]);
            const float* w1 = reinterpret_cast<const float*>(&wv[a][1]);
            const float* x0 = reinterpret_cast<const float*>(&xv[a][0]);
            const float* x1 = reinterpret_cast<const float*>(&xv[a][1]);
            *reinterpret_cast<unsigned*>(&wsm[((u * 4 + j) * 64 + g * 16 + col) * 8 + s]) =
                pk2(__expf(w0[j]), __expf(w1[j]));
            *reinterpret_cast<unsigned*>(&xs[((u * 4 + j) * 64 + g * 16 + col) * 8 + s]) =
                pk2(__expf(x0[j]), __expf(x1[j]));
        }
    }

    __syncthreads();

    // ---- MFMA: wave (wt = n-tile, wu = oc-tile), 4 r-outputs, K=32 each
    const int wave = t >> 6;
    const int wt = wave & 1, wu = wave >> 1;
    const int l  = t & 63;

    f32x4 acc[4];
    #pragma unroll
    for (int j = 0; j < 4; ++j) {
        bf16x8 av = *reinterpret_cast<const bf16x8*>(&xs [((wt * 4 + j) * 64 + l) * 8]);
        bf16x8 bv = *reinterpret_cast<const bf16x8*>(&wsm[((wu * 4 + j) * 64 + l) * 8]);
        f32x4 z = {0.f, 0.f, 0.f, 0.f};
        acc[j] = __builtin_amdgcn_mfma_f32_16x16x32_bf16(av, bv, z, 0, 0, 0);
    }

    // ---- epilogue: log + float4 store (C/D: col = l&15, row = (l>>4)*4 + i)
    const int colL = l & 15, qL = l >> 4;
    #pragma unroll
    for (int i = 0; i < 4; ++i) {
        const int n = n0 + wt * 16 + qL * 4 + i;
        float4 v;
        v.x = __logf(acc[0][i]); v.y = __logf(acc[1][i]);
        v.z = __logf(acc[2][i]); v.w = __logf(acc[3][i]);
        *reinterpret_cast<float4*>(out + (size_t)n * (kD * kOC * kR)
            + (size_t)d * (kOC * kR) + (size_t)(wu * 16 + colL) * 8 + rh * 4) = v;
    }
}

extern "C" void kernel_launch(void* const* d_in, const int* in_sizes, int n_in,
                              void* d_out, int out_size, void* d_ws, size_t ws_size,
                              hipStream_t stream) {
    const float* x = (const float*)d_in[0];
    const float* w = (const float*)d_in[1];
    float* out = (float*)d_out;
    dim3 grid(kD, 8, 2);
    lse_kernel<<<grid, 256, 0, stream>>>(x, w, out);
}